// Round 9
// baseline (664.818 us; speedup 1.0000x reference)
//
#include <hip/hip_runtime.h>
#include <hip/hip_bf16.h>
#include <stdint.h>

// Problem constants
#define B_ 1024
#define T_ 64
#define D_ 256
#define H_ 256
#define G_ 1024   // 4*H

typedef float f32x4 __attribute__((ext_vector_type(4)));
typedef __bf16 bf16x8 __attribute__((ext_vector_type(8)));
typedef unsigned int u32x4 __attribute__((ext_vector_type(4)));

#if __has_builtin(__builtin_amdgcn_rcpf)
#define RCP(x) __builtin_amdgcn_rcpf(x)
#else
#define RCP(x) (1.f / (x))
#endif

__device__ __forceinline__ float bf2f(unsigned int u) {
    unsigned int x = u << 16;
    return __builtin_bit_cast(float, x);
}
__device__ __forceinline__ unsigned short f2bf(float f) {
    __hip_bfloat16 h = __float2bfloat16(f);   // RNE
    return __builtin_bit_cast(unsigned short, h);
}

// ---------------------------------------------------------------------------
// prep_w: W_ih, W_hh f32 -> bf16; bias = b_ih + b_hh.
__global__ void prep_w_kernel(const float* __restrict__ Wih, const float* __restrict__ Whh,
                              const float* __restrict__ bih, const float* __restrict__ bhh,
                              unsigned short* __restrict__ wih_bf, unsigned short* __restrict__ whh_bf,
                              float* __restrict__ bias) {
    int i = blockIdx.x * 256 + threadIdx.x;   // covers G_*D_ exactly
    wih_bf[i] = f2bf(Wih[i]);
    whh_bf[i] = f2bf(Whh[i]);
    if (i < G_) bias[i] = bih[i] + bhh[i];
}

// ---------------------------------------------------------------------------
// prep_attn: attn[b,:] = softmax_d(x_score[b,:]); s_hc and b_attn cancel.
__global__ void prep_attn_kernel(const float* __restrict__ x, const float* __restrict__ Wattn,
                                 float* __restrict__ attn) {
    __shared__ float wx[T_];
    __shared__ float red[256];
    int b = blockIdx.x, d = threadIdx.x;
    if (d < T_) wx[d] = Wattn[2 * H_ + d];
    __syncthreads();
    const float* xb = x + (size_t)b * T_ * D_ + d;
    float s = 0.f;
    #pragma unroll
    for (int t = 0; t < T_; ++t) s += xb[t * D_] * wx[t];
    red[d] = s;
    __syncthreads();
    for (int o = 128; o > 0; o >>= 1) {
        if (d < o) red[d] = fmaxf(red[d], red[d + o]);
        __syncthreads();
    }
    float m = red[0];
    __syncthreads();
    float e = __expf(s - m);
    red[d] = e;
    __syncthreads();
    for (int o = 128; o > 0; o >>= 1) {
        if (d < o) red[d] += red[d + o];
        __syncthreads();
    }
    attn[b * D_ + d] = e * (1.f / red[0]);
}

// ---------------------------------------------------------------------------
// winw: w_in = attn (*) x. f32 out ([b][t][d]) + bf16 copy [t][b][d] for GEMM.
__global__ void winw_kernel(const float* __restrict__ x, const float* __restrict__ attn,
                            float* __restrict__ w_out, unsigned short* __restrict__ win_bf) {
    int i4 = blockIdx.x * 256 + threadIdx.x;  // [0, B*T*D/4)
    int e  = i4 * 4;
    int d  = e & 255;
    int bt = e >> 8;            // b*64 + t
    int b  = bt >> 6, t = bt & 63;
    f32x4 xv = *(const f32x4*)(x + e);
    f32x4 av = *(const f32x4*)(attn + b * D_ + d);
    f32x4 w  = xv * av;
    *(f32x4*)(w_out + e) = w;
    ushort4 u;
    u.x = f2bf(w[0]); u.y = f2bf(w[1]); u.z = f2bf(w[2]); u.w = f2bf(w[3]);
    *(ushort4*)(win_bf + ((size_t)(t * B_ + b) * D_ + d)) = u;
}

// ---------------------------------------------------------------------------
// gemmx: pre_gates[m][n] = sum_k w_in[m][k] * W_ih[n][k], m = t*1024+b.
__global__ __launch_bounds__(256, 2) void gemmx_kernel(const unsigned short* __restrict__ A,
                                                       const unsigned short* __restrict__ Bw,
                                                       unsigned short* __restrict__ pre) {
    int bx = blockIdx.x;               // 4096 = 512 x 8
    int bn = bx & 7, bm = bx >> 3;
    int tid = threadIdx.x, lane = tid & 63, w = tid >> 6;
    int wr = w >> 1, wc = w & 1;
    int m0 = bm * 128 + wr * 64, n0 = bn * 128 + wc * 64;
    int lr = lane & 15, lk = (lane >> 4) * 8;

    const unsigned short* Ab[4];
    const unsigned short* Bb[4];
    #pragma unroll
    for (int i = 0; i < 4; ++i) {
        Ab[i] = A  + (size_t)(m0 + i * 16 + lr) * D_ + lk;
        Bb[i] = Bw + (size_t)(n0 + i * 16 + lr) * D_ + lk;
    }
    f32x4 acc[4][4] = {};
    #pragma unroll
    for (int kk = 0; kk < 8; ++kk) {
        bf16x8 a[4], bb[4];
        #pragma unroll
        for (int i = 0; i < 4; ++i) {
            a[i]  = *(const bf16x8*)(Ab[i] + kk * 32);
            bb[i] = *(const bf16x8*)(Bb[i] + kk * 32);
        }
        #pragma unroll
        for (int mi = 0; mi < 4; ++mi)
            #pragma unroll
            for (int ni = 0; ni < 4; ++ni)
                acc[mi][ni] = __builtin_amdgcn_mfma_f32_16x16x32_bf16(a[mi], bb[ni], acc[mi][ni], 0, 0, 0);
    }
    int orow = (lane >> 4) * 4;
    #pragma unroll
    for (int mi = 0; mi < 4; ++mi)
        #pragma unroll
        for (int ni = 0; ni < 4; ++ni)
            #pragma unroll
            for (int q = 0; q < 4; ++q) {
                int m = m0 + mi * 16 + orow + q;
                int n = n0 + ni * 16 + lr;
                pre[(size_t)m * G_ + n] = f2bf(acc[mi][ni][q]);
            }
}

// ---------------------------------------------------------------------------
// seqs v9: fit the 256-reg unified budget (2 waves/EU): 128 AGPR (4 W tiles,
// "+a") + arch <= ~124: sbuf 32 + pre 32 + acc 16 + bias/c 16 + misc.
// Rounds 5/7/8 all spilled (~290 demand vs 256 budget, VGPR_Count pinned at
// 128) -> scratch traffic was the invariant 5 us/step. W placement: 4 AGPR +
// 2 LDS + 2 streamed (L2-hot). Stream MFMAs ordered LAST in phase B so the
// mid-phase reload has max cover; next-step kk0-3 crosses the barrier in
// flight. Pre-gates: dword-pair loads prefetched one full step ahead.
__global__ __launch_bounds__(512)
__attribute__((amdgpu_waves_per_eu(2, 2)))
void seqs_kernel(const unsigned short* __restrict__ pre,
                 const unsigned short* __restrict__ Whh,
                 const float* __restrict__ bias,
                 float* __restrict__ enc_out) {
    extern __shared__ char smem[];
    unsigned short* W_frag = (unsigned short*)smem;              // [8w][2l][8kk][64lane][8] = 131072 B
    unsigned short* h_frag = (unsigned short*)(smem + 131072);   // [2par][8kk][64lane][8] = 16384 B

    int tid = threadIdx.x, lane = tid & 63, w = tid >> 6;
    int lr = lane & 15, hi = lane >> 4;
    int r0 = blockIdx.x * 16;
    int j0 = w * 32;

    // --- stage LDS W tiles (jt=1, g=0,1) in fragment layout ----------------
    #pragma unroll
    for (int l = 0; l < 2; ++l) {
        int n = l * 256 + j0 + 16 + lr;
        const unsigned short* src = Whh + (size_t)n * 256 + hi * 8;
        #pragma unroll
        for (int c = 0; c < 8; ++c)
            *(u32x4*)&W_frag[(((w * 2 + l) * 8 + c) * 64 + lane) * 8] =
                *(const u32x4*)(src + c * 32);
    }
    // zero h (both parities)
    for (int i = tid; i < 4096; i += 512) ((unsigned int*)h_frag)[i] = 0;

    // --- AGPR W tiles (jt=0, g=0..3): 128 acc regs -------------------------
    bf16x8 Wreg[4][8];
    #pragma unroll
    for (int g = 0; g < 4; ++g)
        #pragma unroll
        for (int kk = 0; kk < 8; ++kk)
            Wreg[g][kk] = *(const bf16x8*)(Whh + (size_t)(g * 256 + j0 + lr) * 256 + kk * 32 + hi * 8);
    #pragma unroll
    for (int g = 0; g < 4; ++g)
        #pragma unroll
        for (int kk = 0; kk < 8; ++kk)
            asm volatile("" : "+a"(Wreg[g][kk]));   // pin to AGPRs, block remat

    // --- stream-tile pointers (jt=1, g=2,3) + prologue kk0-3 ---------------
    const unsigned short* Ws0 = Whh + (size_t)(2 * 256 + j0 + 16 + lr) * 256 + hi * 8;
    const unsigned short* Ws1 = Whh + (size_t)(3 * 256 + j0 + 16 + lr) * 256 + hi * 8;
    bf16x8 sbuf[2][4];
    #pragma unroll
    for (int k2 = 0; k2 < 4; ++k2) {
        sbuf[0][k2] = *(const bf16x8*)(Ws0 + k2 * 32);
        sbuf[1][k2] = *(const bf16x8*)(Ws1 + k2 * 32);
    }

    // pre-gate pair-load base: lane covers col pair (lr&14, lr&14|1)
    const unsigned short* ppair = pre + (size_t)(r0 + hi * 4) * G_ + j0 + (lr & 14);
    unsigned int sel = (lr & 1);
    float biasA[4], biasB[4];
    #pragma unroll
    for (int g = 0; g < 4; ++g) {
        biasA[g] = bias[g * 256 + j0 + lr];
        biasB[g] = bias[g * 256 + j0 + 16 + lr];
    }
    float cA[4] = {}, cB[4] = {};

    // prologue: pre-gates for t=0
    unsigned int pA[16], pB[16];
    #pragma unroll
    for (int g = 0; g < 4; ++g)
        #pragma unroll
        for (int q = 0; q < 4; ++q) {
            pA[g * 4 + q] = *(const unsigned int*)(ppair + (size_t)q * 1024 + g * 256);
            pB[g * 4 + q] = *(const unsigned int*)(ppair + (size_t)q * 1024 + g * 256 + 16);
        }

    __syncthreads();

    #pragma unroll 1
    for (int t = 0; t < T_; ++t) {
        // next-step pre base (clamped: t=63 re-reads t=63, values unused)
        const unsigned short* Pn = ppair + (size_t)(t < 63 ? t + 1 : 63) * (1024u * 1024u);

        int p = t & 1;
        const unsigned short* hrd = h_frag + p * 4096;
        unsigned short*       hwr = h_frag + (p ^ 1) * 4096;

        // ---- Phase A K-loop: jt=0, 4 tiles from AGPRs ----------------------
        f32x4 acc[4] = {};
        #pragma unroll
        for (int kk = 0; kk < 8; ++kk) {
            bf16x8 a = *(const bf16x8*)&hrd[(kk * 64 + lane) * 8];
            #pragma unroll
            for (int g = 0; g < 4; ++g)
                acc[g] = __builtin_amdgcn_mfma_f32_16x16x32_bf16(a, Wreg[g][kk], acc[g], 0, 0, 0);
        }

        // ---- Phase A cell update (consumes pA), then prefetch pA(t+1) ------
        #pragma unroll
        for (int q = 0; q < 4; ++q) {
            float gi = acc[0][q] + __builtin_bit_cast(float, sel ? (pA[0 * 4 + q] & 0xffff0000u) : (pA[0 * 4 + q] << 16)) + biasA[0];
            float gf = acc[1][q] + __builtin_bit_cast(float, sel ? (pA[1 * 4 + q] & 0xffff0000u) : (pA[1 * 4 + q] << 16)) + biasA[1];
            float gg = acc[2][q] + __builtin_bit_cast(float, sel ? (pA[2 * 4 + q] & 0xffff0000u) : (pA[2 * 4 + q] << 16)) + biasA[2];
            float go = acc[3][q] + __builtin_bit_cast(float, sel ? (pA[3 * 4 + q] & 0xffff0000u) : (pA[3 * 4 + q] << 16)) + biasA[3];
            float si = RCP(1.f + __expf(-gi));
            float sf = RCP(1.f + __expf(-gf));
            float so = RCP(1.f + __expf(-go));
            float tg = 1.f - 2.f * RCP(__expf(2.f * gg) + 1.f);
            float cn = sf * cA[q] + si * tg;
            cA[q] = cn;
            float tc = 1.f - 2.f * RCP(__expf(2.f * cn) + 1.f);
            float h  = so * tc;
            unsigned int hu = (unsigned int)f2bf(h);
            unsigned int ph = (unsigned int)__shfl_xor((int)hu, 1);
            if ((lr & 1) == 0) {
                unsigned int dw = hu | (ph << 16);
                *(unsigned int*)&hwr[w * 512 + (((lr >> 3) * 16) + hi * 4 + q) * 8 + (lr & 7)] = dw;
            }
            enc_out[((size_t)(r0 + hi * 4 + q) * T_ + t) * H_ + j0 + lr] = h;
        }
        // prefetch pA for t+1 (cover ~ full remaining step + barrier)
        #pragma unroll
        for (int g = 0; g < 4; ++g)
            #pragma unroll
            for (int q = 0; q < 4; ++q)
                pA[g * 4 + q] = *(const unsigned int*)(Pn + (size_t)q * 1024 + g * 256);

        // ---- Phase B: jt=1. LDS-tile MFMAs first, stream MFMAs last --------
        f32x4 accB[4] = {};
        // B1: kk0-3, all four tiles (sbuf holds kk0-3)
        #pragma unroll
        for (int kk = 0; kk < 4; ++kk) {
            bf16x8 a  = *(const bf16x8*)&hrd[(kk * 64 + lane) * 8];
            bf16x8 b0 = *(const bf16x8*)&W_frag[(((w * 2 + 0) * 8 + kk) * 64 + lane) * 8];
            bf16x8 b1 = *(const bf16x8*)&W_frag[(((w * 2 + 1) * 8 + kk) * 64 + lane) * 8];
            accB[0] = __builtin_amdgcn_mfma_f32_16x16x32_bf16(a, b0, accB[0], 0, 0, 0);
            accB[1] = __builtin_amdgcn_mfma_f32_16x16x32_bf16(a, b1, accB[1], 0, 0, 0);
            accB[2] = __builtin_amdgcn_mfma_f32_16x16x32_bf16(a, sbuf[0][kk], accB[2], 0, 0, 0);
            accB[3] = __builtin_amdgcn_mfma_f32_16x16x32_bf16(a, sbuf[1][kk], accB[3], 0, 0, 0);
        }
        // reload sbuf with kk4-7 (consumed in B3, after 8 LDS MFMAs of cover)
        #pragma unroll
        for (int k2 = 0; k2 < 4; ++k2) {
            sbuf[0][k2] = *(const bf16x8*)(Ws0 + (k2 + 4) * 32);
            sbuf[1][k2] = *(const bf16x8*)(Ws1 + (k2 + 4) * 32);
        }
        // B2: kk4-7, LDS tiles only
        bf16x8 a47[4];
        #pragma unroll
        for (int kk = 4; kk < 8; ++kk) {
            bf16x8 a  = *(const bf16x8*)&hrd[(kk * 64 + lane) * 8];
            a47[kk - 4] = a;
            bf16x8 b0 = *(const bf16x8*)&W_frag[(((w * 2 + 0) * 8 + kk) * 64 + lane) * 8];
            bf16x8 b1 = *(const bf16x8*)&W_frag[(((w * 2 + 1) * 8 + kk) * 64 + lane) * 8];
            accB[0] = __builtin_amdgcn_mfma_f32_16x16x32_bf16(a, b0, accB[0], 0, 0, 0);
            accB[1] = __builtin_amdgcn_mfma_f32_16x16x32_bf16(a, b1, accB[1], 0, 0, 0);
        }
        // B3: kk4-7, stream tiles
        #pragma unroll
        for (int kk = 0; kk < 4; ++kk) {
            accB[2] = __builtin_amdgcn_mfma_f32_16x16x32_bf16(a47[kk], sbuf[0][kk], accB[2], 0, 0, 0);
            accB[3] = __builtin_amdgcn_mfma_f32_16x16x32_bf16(a47[kk], sbuf[1][kk], accB[3], 0, 0, 0);
        }
        // reload sbuf with kk0-3 for NEXT step (in flight across the barrier)
        #pragma unroll
        for (int k2 = 0; k2 < 4; ++k2) {
            sbuf[0][k2] = *(const bf16x8*)(Ws0 + k2 * 32);
            sbuf[1][k2] = *(const bf16x8*)(Ws1 + k2 * 32);
        }

        // ---- Phase B cell update (consumes pB), then prefetch pB(t+1) ------
        #pragma unroll
        for (int q = 0; q < 4; ++q) {
            float gi = accB[0][q] + __builtin_bit_cast(float, sel ? (pB[0 * 4 + q] & 0xffff0000u) : (pB[0 * 4 + q] << 16)) + biasB[0];
            float gf = accB[1][q] + __builtin_bit_cast(float, sel ? (pB[1 * 4 + q] & 0xffff0000u) : (pB[1 * 4 + q] << 16)) + biasB[1];
            float gg = accB[2][q] + __builtin_bit_cast(float, sel ? (pB[2 * 4 + q] & 0xffff0000u) : (pB[2 * 4 + q] << 16)) + biasB[2];
            float go = accB[3][q] + __builtin_bit_cast(float, sel ? (pB[3 * 4 + q] & 0xffff0000u) : (pB[3 * 4 + q] << 16)) + biasB[3];
            float si = RCP(1.f + __expf(-gi));
            float sf = RCP(1.f + __expf(-gf));
            float so = RCP(1.f + __expf(-go));
            float tg = 1.f - 2.f * RCP(__expf(2.f * gg) + 1.f);
            float cn = sf * cB[q] + si * tg;
            cB[q] = cn;
            float tc = 1.f - 2.f * RCP(__expf(2.f * cn) + 1.f);
            float h  = so * tc;
            unsigned int hu = (unsigned int)f2bf(h);
            unsigned int ph = (unsigned int)__shfl_xor((int)hu, 1);
            if ((lr & 1) == 0) {
                unsigned int dw = hu | (ph << 16);
                *(unsigned int*)&hwr[w * 512 + ((32 + (lr >> 3) * 16) + hi * 4 + q) * 8 + (lr & 7)] = dw;
            }
            enc_out[((size_t)(r0 + hi * 4 + q) * T_ + t) * H_ + j0 + 16 + lr] = h;
        }
        // prefetch pB for t+1
        #pragma unroll
        for (int g = 0; g < 4; ++g)
            #pragma unroll
            for (int q = 0; q < 4; ++q)
                pB[g * 4 + q] = *(const unsigned int*)(Pn + (size_t)q * 1024 + g * 256 + 16);

        // end of step: only LDS must drain; vmem stays in flight
        asm volatile("s_waitcnt lgkmcnt(0)" ::: "memory");
        __builtin_amdgcn_s_barrier();
        __builtin_amdgcn_sched_barrier(0);
    }
}

// ---------------------------------------------------------------------------
extern "C" void kernel_launch(void* const* d_in, const int* in_sizes, int n_in,
                              void* d_out, int out_size, void* d_ws, size_t ws_size,
                              hipStream_t stream) {
    const float* x     = (const float*)d_in[0];
    const float* Wattn = (const float*)d_in[1];
    // d_in[2] = b_attn (cancels in softmax)
    const float* Wih   = (const float*)d_in[3];
    const float* Whh   = (const float*)d_in[4];
    const float* bih   = (const float*)d_in[5];
    const float* bhh   = (const float*)d_in[6];

    char* ws = (char*)d_ws;
    float*          attn   = (float*)(ws);                            // 1 MB
    unsigned short* win_bf = (unsigned short*)(ws + 1048576);         // 32 MB [t][b][d]
    unsigned short* wih_bf = (unsigned short*)(ws + 34603008);        // 512 KB
    unsigned short* whh_bf = (unsigned short*)(ws + 35127296);        // 512 KB
    float*          bias   = (float*)(ws + 35651584);                 // 4 KB
    unsigned short* pre    = (unsigned short*)(ws + 35659776);        // 128 MB [t][b][n]

    float* w_out   = (float*)d_out;                                   // output 0
    float* enc_out = (float*)d_out + (size_t)B_ * T_ * D_;            // output 1

    hipFuncSetAttribute((const void*)seqs_kernel,
                        hipFuncAttributeMaxDynamicSharedMemorySize, 147456);

    prep_w_kernel<<<dim3(1024), dim3(256), 0, stream>>>(Wih, Whh, bih, bhh, wih_bf, whh_bf, bias);
    prep_attn_kernel<<<dim3(1024), dim3(256), 0, stream>>>(x, Wattn, attn);
    winw_kernel<<<dim3(16384), dim3(256), 0, stream>>>(x, attn, w_out, win_bf);
    gemmx_kernel<<<dim3(4096), dim3(256), 0, stream>>>(win_bf, wih_bf, pre);
    seqs_kernel<<<dim3(64), dim3(512), 147456, stream>>>(pre, whh_bf, bias, enc_out);
}

// Round 10
// 574.315 us; speedup vs baseline: 1.1576x; 1.1576x over previous
//
#include <hip/hip_runtime.h>
#include <hip/hip_bf16.h>
#include <stdint.h>

// Problem constants
#define B_ 1024
#define T_ 64
#define D_ 256
#define H_ 256
#define G_ 1024   // 4*H

typedef float f32x4 __attribute__((ext_vector_type(4)));
typedef __bf16 bf16x8 __attribute__((ext_vector_type(8)));
typedef unsigned int u32x4 __attribute__((ext_vector_type(4)));

#if __has_builtin(__builtin_amdgcn_rcpf)
#define RCP(x) __builtin_amdgcn_rcpf(x)
#else
#define RCP(x) (1.f / (x))
#endif

__device__ __forceinline__ float bf2f(unsigned int u) {
    unsigned int x = u << 16;
    return __builtin_bit_cast(float, x);
}
__device__ __forceinline__ unsigned short f2bf(float f) {
    __hip_bfloat16 h = __float2bfloat16(f);   // RNE
    return __builtin_bit_cast(unsigned short, h);
}

// ---------------------------------------------------------------------------
// prep_w: W_ih, W_hh f32 -> bf16; bias = b_ih + b_hh.
__global__ void prep_w_kernel(const float* __restrict__ Wih, const float* __restrict__ Whh,
                              const float* __restrict__ bih, const float* __restrict__ bhh,
                              unsigned short* __restrict__ wih_bf, unsigned short* __restrict__ whh_bf,
                              float* __restrict__ bias) {
    int i = blockIdx.x * 256 + threadIdx.x;   // covers G_*D_ exactly
    wih_bf[i] = f2bf(Wih[i]);
    whh_bf[i] = f2bf(Whh[i]);
    if (i < G_) bias[i] = bih[i] + bhh[i];
}

// ---------------------------------------------------------------------------
// prep_attn: attn[b,:] = softmax_d(x_score[b,:]); s_hc and b_attn cancel.
__global__ void prep_attn_kernel(const float* __restrict__ x, const float* __restrict__ Wattn,
                                 float* __restrict__ attn) {
    __shared__ float wx[T_];
    __shared__ float red[256];
    int b = blockIdx.x, d = threadIdx.x;
    if (d < T_) wx[d] = Wattn[2 * H_ + d];
    __syncthreads();
    const float* xb = x + (size_t)b * T_ * D_ + d;
    float s = 0.f;
    #pragma unroll
    for (int t = 0; t < T_; ++t) s += xb[t * D_] * wx[t];
    red[d] = s;
    __syncthreads();
    for (int o = 128; o > 0; o >>= 1) {
        if (d < o) red[d] = fmaxf(red[d], red[d + o]);
        __syncthreads();
    }
    float m = red[0];
    __syncthreads();
    float e = __expf(s - m);
    red[d] = e;
    __syncthreads();
    for (int o = 128; o > 0; o >>= 1) {
        if (d < o) red[d] += red[d + o];
        __syncthreads();
    }
    attn[b * D_ + d] = e * (1.f / red[0]);
}

// ---------------------------------------------------------------------------
// winw: w_in = attn (*) x. f32 out ([b][t][d]) + bf16 copy [t][b][d] for GEMM.
__global__ void winw_kernel(const float* __restrict__ x, const float* __restrict__ attn,
                            float* __restrict__ w_out, unsigned short* __restrict__ win_bf) {
    int i4 = blockIdx.x * 256 + threadIdx.x;  // [0, B*T*D/4)
    int e  = i4 * 4;
    int d  = e & 255;
    int bt = e >> 8;            // b*64 + t
    int b  = bt >> 6, t = bt & 63;
    f32x4 xv = *(const f32x4*)(x + e);
    f32x4 av = *(const f32x4*)(attn + b * D_ + d);
    f32x4 w  = xv * av;
    *(f32x4*)(w_out + e) = w;
    ushort4 u;
    u.x = f2bf(w[0]); u.y = f2bf(w[1]); u.z = f2bf(w[2]); u.w = f2bf(w[3]);
    *(ushort4*)(win_bf + ((size_t)(t * B_ + b) * D_ + d)) = u;
}

// ---------------------------------------------------------------------------
// gemmx: pre_gates[m][n] = sum_k w_in[m][k] * W_ih[n][k] + bias[n]  (bias
// folded here so seqs doesn't need bias registers), m = t*1024+b.
__global__ __launch_bounds__(256, 2) void gemmx_kernel(const unsigned short* __restrict__ A,
                                                       const unsigned short* __restrict__ Bw,
                                                       const float* __restrict__ bias,
                                                       unsigned short* __restrict__ pre) {
    int bx = blockIdx.x;               // 4096 = 512 x 8
    int bn = bx & 7, bm = bx >> 3;
    int tid = threadIdx.x, lane = tid & 63, w = tid >> 6;
    int wr = w >> 1, wc = w & 1;
    int m0 = bm * 128 + wr * 64, n0 = bn * 128 + wc * 64;
    int lr = lane & 15, lk = (lane >> 4) * 8;

    const unsigned short* Ab[4];
    const unsigned short* Bb[4];
    float biasv[4];
    #pragma unroll
    for (int i = 0; i < 4; ++i) {
        Ab[i] = A  + (size_t)(m0 + i * 16 + lr) * D_ + lk;
        Bb[i] = Bw + (size_t)(n0 + i * 16 + lr) * D_ + lk;
        biasv[i] = bias[n0 + i * 16 + lr];
    }
    f32x4 acc[4][4] = {};
    #pragma unroll
    for (int kk = 0; kk < 8; ++kk) {
        bf16x8 a[4], bb[4];
        #pragma unroll
        for (int i = 0; i < 4; ++i) {
            a[i]  = *(const bf16x8*)(Ab[i] + kk * 32);
            bb[i] = *(const bf16x8*)(Bb[i] + kk * 32);
        }
        #pragma unroll
        for (int mi = 0; mi < 4; ++mi)
            #pragma unroll
            for (int ni = 0; ni < 4; ++ni)
                acc[mi][ni] = __builtin_amdgcn_mfma_f32_16x16x32_bf16(a[mi], bb[ni], acc[mi][ni], 0, 0, 0);
    }
    int orow = (lane >> 4) * 4;
    #pragma unroll
    for (int mi = 0; mi < 4; ++mi)
        #pragma unroll
        for (int ni = 0; ni < 4; ++ni)
            #pragma unroll
            for (int q = 0; q < 4; ++q) {
                int m = m0 + mi * 16 + orow + q;
                int n = n0 + ni * 16 + lr;
                pre[(size_t)m * G_ + n] = f2bf(acc[mi][ni][q] + biasv[ni]);
            }
}

// ---------------------------------------------------------------------------
// seqs v10: arch register demand trimmed to <= 128 (the cap left by 128
// laundered AGPRs at 2 waves/EU). v5-v9 all exceeded it and spilled -> the
// invariant ~5 us/step was scratch reload latency. Cuts: bias folded into
// gemmx; pB(t) loaded at step top / pA(t+1) at step end (16+16, brief
// overlap) instead of 32 always-live; a47 dropped (h re-read from LDS);
// sched_barrier keeps acc/accB live ranges disjoint.
__global__ __launch_bounds__(512)
__attribute__((amdgpu_waves_per_eu(2, 2)))
void seqs_kernel(const unsigned short* __restrict__ pre,
                 const unsigned short* __restrict__ Whh,
                 float* __restrict__ enc_out) {
    extern __shared__ char smem[];
    unsigned short* W_frag = (unsigned short*)smem;              // [8w][2l][8kk][64lane][8] = 131072 B
    unsigned short* h_frag = (unsigned short*)(smem + 131072);   // [2par][8kk][64lane][8] = 16384 B

    int tid = threadIdx.x, lane = tid & 63, w = tid >> 6;
    int lr = lane & 15, hi = lane >> 4;
    int r0 = blockIdx.x * 16;
    int j0 = w * 32;

    // --- stage LDS W tiles (jt=1, g=0,1) in fragment layout ----------------
    #pragma unroll
    for (int l = 0; l < 2; ++l) {
        int n = l * 256 + j0 + 16 + lr;
        const unsigned short* src = Whh + (size_t)n * 256 + hi * 8;
        #pragma unroll
        for (int c = 0; c < 8; ++c)
            *(u32x4*)&W_frag[(((w * 2 + l) * 8 + c) * 64 + lane) * 8] =
                *(const u32x4*)(src + c * 32);
    }
    // zero h (both parities)
    for (int i = tid; i < 4096; i += 512) ((unsigned int*)h_frag)[i] = 0;

    // --- AGPR W tiles (jt=0, g=0..3): 128 acc regs -------------------------
    bf16x8 Wreg[4][8];
    #pragma unroll
    for (int g = 0; g < 4; ++g)
        #pragma unroll
        for (int kk = 0; kk < 8; ++kk)
            Wreg[g][kk] = *(const bf16x8*)(Whh + (size_t)(g * 256 + j0 + lr) * 256 + kk * 32 + hi * 8);
    #pragma unroll
    for (int g = 0; g < 4; ++g)
        #pragma unroll
        for (int kk = 0; kk < 8; ++kk)
            asm volatile("" : "+a"(Wreg[g][kk]));   // pin to AGPRs, block remat

    // --- stream-tile pointers (jt=1, g=2,3) + prologue kk0-3 ---------------
    const unsigned short* Ws0 = Whh + (size_t)(2 * 256 + j0 + 16 + lr) * 256 + hi * 8;
    const unsigned short* Ws1 = Whh + (size_t)(3 * 256 + j0 + 16 + lr) * 256 + hi * 8;
    bf16x8 sbuf[2][4];
    #pragma unroll
    for (int k2 = 0; k2 < 4; ++k2) {
        sbuf[0][k2] = *(const bf16x8*)(Ws0 + k2 * 32);
        sbuf[1][k2] = *(const bf16x8*)(Ws1 + k2 * 32);
    }

    // pre-gate pair-load base: lane covers col pair (lr&14, lr&14|1)
    const unsigned short* ppair = pre + (size_t)(r0 + hi * 4) * G_ + j0 + (lr & 14);
    unsigned int sel = (lr & 1);
    float cA[4] = {}, cB[4] = {};

    // prologue: pA for t=0
    unsigned int pA[16];
    #pragma unroll
    for (int g = 0; g < 4; ++g)
        #pragma unroll
        for (int q = 0; q < 4; ++q)
            pA[g * 4 + q] = *(const unsigned int*)(ppair + (size_t)q * 1024 + g * 256);

    __syncthreads();

    #pragma unroll 1
    for (int t = 0; t < T_; ++t) {
        const unsigned short* Ps = ppair + (size_t)t * (1024u * 1024u);

        // pB(t): issued at step top, consumed at cell B (~1500 cy away)
        unsigned int pB[16];
        #pragma unroll
        for (int g = 0; g < 4; ++g)
            #pragma unroll
            for (int q = 0; q < 4; ++q)
                pB[g * 4 + q] = *(const unsigned int*)(Ps + (size_t)q * 1024 + g * 256 + 16);

        int p = t & 1;
        const unsigned short* hrd = h_frag + p * 4096;
        unsigned short*       hwr = h_frag + (p ^ 1) * 4096;

        // ---- Phase A K-loop: jt=0, 4 tiles from AGPRs ----------------------
        f32x4 acc[4] = {};
        #pragma unroll
        for (int kk = 0; kk < 8; ++kk) {
            bf16x8 a = *(const bf16x8*)&hrd[(kk * 64 + lane) * 8];
            #pragma unroll
            for (int g = 0; g < 4; ++g)
                acc[g] = __builtin_amdgcn_mfma_f32_16x16x32_bf16(a, Wreg[g][kk], acc[g], 0, 0, 0);
        }

        // ---- Phase A cell update (consumes acc + pA) -----------------------
        #pragma unroll
        for (int q = 0; q < 4; ++q) {
            float gi = acc[0][q] + __builtin_bit_cast(float, sel ? (pA[0 * 4 + q] & 0xffff0000u) : (pA[0 * 4 + q] << 16));
            float gf = acc[1][q] + __builtin_bit_cast(float, sel ? (pA[1 * 4 + q] & 0xffff0000u) : (pA[1 * 4 + q] << 16));
            float gg = acc[2][q] + __builtin_bit_cast(float, sel ? (pA[2 * 4 + q] & 0xffff0000u) : (pA[2 * 4 + q] << 16));
            float go = acc[3][q] + __builtin_bit_cast(float, sel ? (pA[3 * 4 + q] & 0xffff0000u) : (pA[3 * 4 + q] << 16));
            float si = RCP(1.f + __expf(-gi));
            float sf = RCP(1.f + __expf(-gf));
            float so = RCP(1.f + __expf(-go));
            float tg = 1.f - 2.f * RCP(__expf(2.f * gg) + 1.f);
            float cn = sf * cA[q] + si * tg;
            cA[q] = cn;
            float tc = 1.f - 2.f * RCP(__expf(2.f * cn) + 1.f);
            float h  = so * tc;
            unsigned int hu = (unsigned int)f2bf(h);
            unsigned int ph = (unsigned int)__shfl_xor((int)hu, 1);
            if ((lr & 1) == 0) {
                unsigned int dw = hu | (ph << 16);
                *(unsigned int*)&hwr[w * 512 + (((lr >> 3) * 16) + hi * 4 + q) * 8 + (lr & 7)] = dw;
            }
            enc_out[((size_t)(r0 + hi * 4 + q) * T_ + t) * H_ + j0 + lr] = h;
        }
        __builtin_amdgcn_sched_barrier(0);   // acc dead before accB born

        // ---- Phase B: jt=1 -------------------------------------------------
        f32x4 accB[4] = {};
        // B1: kk0-3, all four tiles (sbuf holds kk0-3)
        #pragma unroll
        for (int kk = 0; kk < 4; ++kk) {
            bf16x8 a  = *(const bf16x8*)&hrd[(kk * 64 + lane) * 8];
            bf16x8 b0 = *(const bf16x8*)&W_frag[(((w * 2 + 0) * 8 + kk) * 64 + lane) * 8];
            bf16x8 b1 = *(const bf16x8*)&W_frag[(((w * 2 + 1) * 8 + kk) * 64 + lane) * 8];
            accB[0] = __builtin_amdgcn_mfma_f32_16x16x32_bf16(a, b0, accB[0], 0, 0, 0);
            accB[1] = __builtin_amdgcn_mfma_f32_16x16x32_bf16(a, b1, accB[1], 0, 0, 0);
            accB[2] = __builtin_amdgcn_mfma_f32_16x16x32_bf16(a, sbuf[0][kk], accB[2], 0, 0, 0);
            accB[3] = __builtin_amdgcn_mfma_f32_16x16x32_bf16(a, sbuf[1][kk], accB[3], 0, 0, 0);
        }
        // reload sbuf with kk4-7 (consumed in B3 after 8 static MFMAs of cover)
        #pragma unroll
        for (int k2 = 0; k2 < 4; ++k2) {
            sbuf[0][k2] = *(const bf16x8*)(Ws0 + (k2 + 4) * 32);
            sbuf[1][k2] = *(const bf16x8*)(Ws1 + (k2 + 4) * 32);
        }
        // B2: kk4-7, static LDS tiles
        #pragma unroll
        for (int kk = 4; kk < 8; ++kk) {
            bf16x8 a  = *(const bf16x8*)&hrd[(kk * 64 + lane) * 8];
            bf16x8 b0 = *(const bf16x8*)&W_frag[(((w * 2 + 0) * 8 + kk) * 64 + lane) * 8];
            bf16x8 b1 = *(const bf16x8*)&W_frag[(((w * 2 + 1) * 8 + kk) * 64 + lane) * 8];
            accB[0] = __builtin_amdgcn_mfma_f32_16x16x32_bf16(a, b0, accB[0], 0, 0, 0);
            accB[1] = __builtin_amdgcn_mfma_f32_16x16x32_bf16(a, b1, accB[1], 0, 0, 0);
        }
        // B3: kk4-7, stream tiles (h re-read from LDS; a47 buffer removed)
        #pragma unroll
        for (int kk = 4; kk < 8; ++kk) {
            bf16x8 a = *(const bf16x8*)&hrd[(kk * 64 + lane) * 8];
            accB[2] = __builtin_amdgcn_mfma_f32_16x16x32_bf16(a, sbuf[0][kk - 4], accB[2], 0, 0, 0);
            accB[3] = __builtin_amdgcn_mfma_f32_16x16x32_bf16(a, sbuf[1][kk - 4], accB[3], 0, 0, 0);
        }
        // reload sbuf with kk0-3 for NEXT step (in flight across the barrier)
        #pragma unroll
        for (int k2 = 0; k2 < 4; ++k2) {
            sbuf[0][k2] = *(const bf16x8*)(Ws0 + k2 * 32);
            sbuf[1][k2] = *(const bf16x8*)(Ws1 + k2 * 32);
        }

        // ---- Phase B cell update (consumes accB + pB) ----------------------
        #pragma unroll
        for (int q = 0; q < 4; ++q) {
            float gi = accB[0][q] + __builtin_bit_cast(float, sel ? (pB[0 * 4 + q] & 0xffff0000u) : (pB[0 * 4 + q] << 16));
            float gf = accB[1][q] + __builtin_bit_cast(float, sel ? (pB[1 * 4 + q] & 0xffff0000u) : (pB[1 * 4 + q] << 16));
            float gg = accB[2][q] + __builtin_bit_cast(float, sel ? (pB[2 * 4 + q] & 0xffff0000u) : (pB[2 * 4 + q] << 16));
            float go = accB[3][q] + __builtin_bit_cast(float, sel ? (pB[3 * 4 + q] & 0xffff0000u) : (pB[3 * 4 + q] << 16));
            float si = RCP(1.f + __expf(-gi));
            float sf = RCP(1.f + __expf(-gf));
            float so = RCP(1.f + __expf(-go));
            float tg = 1.f - 2.f * RCP(__expf(2.f * gg) + 1.f);
            float cn = sf * cB[q] + si * tg;
            cB[q] = cn;
            float tc = 1.f - 2.f * RCP(__expf(2.f * cn) + 1.f);
            float h  = so * tc;
            unsigned int hu = (unsigned int)f2bf(h);
            unsigned int ph = (unsigned int)__shfl_xor((int)hu, 1);
            if ((lr & 1) == 0) {
                unsigned int dw = hu | (ph << 16);
                *(unsigned int*)&hwr[w * 512 + ((32 + (lr >> 3) * 16) + hi * 4 + q) * 8 + (lr & 7)] = dw;
            }
            enc_out[((size_t)(r0 + hi * 4 + q) * T_ + t) * H_ + j0 + 16 + lr] = h;
        }

        // pA(t+1): issued here, lives across the barrier, consumed at cell A
        {
            const unsigned short* Pn = ppair + (size_t)(t < 63 ? t + 1 : 63) * (1024u * 1024u);
            #pragma unroll
            for (int g = 0; g < 4; ++g)
                #pragma unroll
                for (int q = 0; q < 4; ++q)
                    pA[g * 4 + q] = *(const unsigned int*)(Pn + (size_t)q * 1024 + g * 256);
        }

        // end of step: only LDS must drain; vmem stays in flight
        asm volatile("s_waitcnt lgkmcnt(0)" ::: "memory");
        __builtin_amdgcn_s_barrier();
        __builtin_amdgcn_sched_barrier(0);
    }
}

// ---------------------------------------------------------------------------
extern "C" void kernel_launch(void* const* d_in, const int* in_sizes, int n_in,
                              void* d_out, int out_size, void* d_ws, size_t ws_size,
                              hipStream_t stream) {
    const float* x     = (const float*)d_in[0];
    const float* Wattn = (const float*)d_in[1];
    // d_in[2] = b_attn (cancels in softmax)
    const float* Wih   = (const float*)d_in[3];
    const float* Whh   = (const float*)d_in[4];
    const float* bih   = (const float*)d_in[5];
    const float* bhh   = (const float*)d_in[6];

    char* ws = (char*)d_ws;
    float*          attn   = (float*)(ws);                            // 1 MB
    unsigned short* win_bf = (unsigned short*)(ws + 1048576);         // 32 MB [t][b][d]
    unsigned short* wih_bf = (unsigned short*)(ws + 34603008);        // 512 KB
    unsigned short* whh_bf = (unsigned short*)(ws + 35127296);        // 512 KB
    float*          bias   = (float*)(ws + 35651584);                 // 4 KB
    unsigned short* pre    = (unsigned short*)(ws + 35659776);        // 128 MB [t][b][n]

    float* w_out   = (float*)d_out;                                   // output 0
    float* enc_out = (float*)d_out + (size_t)B_ * T_ * D_;            // output 1

    hipFuncSetAttribute((const void*)seqs_kernel,
                        hipFuncAttributeMaxDynamicSharedMemorySize, 147456);

    prep_w_kernel<<<dim3(1024), dim3(256), 0, stream>>>(Wih, Whh, bih, bhh, wih_bf, whh_bf, bias);
    prep_attn_kernel<<<dim3(1024), dim3(256), 0, stream>>>(x, Wattn, attn);
    winw_kernel<<<dim3(16384), dim3(256), 0, stream>>>(x, attn, w_out, win_bf);
    gemmx_kernel<<<dim3(4096), dim3(256), 0, stream>>>(win_bf, wih_bf, bias, pre);
    seqs_kernel<<<dim3(64), dim3(512), 147456, stream>>>(pre, whh_bf, enc_out);
}

// Round 11
// 471.486 us; speedup vs baseline: 1.4100x; 1.2181x over previous
//
#include <hip/hip_runtime.h>
#include <hip/hip_bf16.h>
#include <stdint.h>

// Problem constants
#define B_ 1024
#define T_ 64
#define D_ 256
#define H_ 256
#define G_ 1024   // 4*H

typedef float f32x4 __attribute__((ext_vector_type(4)));
typedef __bf16 bf16x8 __attribute__((ext_vector_type(8)));
typedef unsigned int u32x4 __attribute__((ext_vector_type(4)));

#if __has_builtin(__builtin_amdgcn_rcpf)
#define RCP(x) __builtin_amdgcn_rcpf(x)
#else
#define RCP(x) (1.f / (x))
#endif

__device__ __forceinline__ unsigned short f2bf(float f) {
    __hip_bfloat16 h = __float2bfloat16(f);   // RNE
    return __builtin_bit_cast(unsigned short, h);
}

// ---------------------------------------------------------------------------
// prep_w: W_ih, W_hh f32 -> bf16; bias = b_ih + b_hh.
__global__ void prep_w_kernel(const float* __restrict__ Wih, const float* __restrict__ Whh,
                              const float* __restrict__ bih, const float* __restrict__ bhh,
                              unsigned short* __restrict__ wih_bf, unsigned short* __restrict__ whh_bf,
                              float* __restrict__ bias) {
    int i = blockIdx.x * 256 + threadIdx.x;   // covers G_*D_ exactly
    wih_bf[i] = f2bf(Wih[i]);
    whh_bf[i] = f2bf(Whh[i]);
    if (i < G_) bias[i] = bih[i] + bhh[i];
}

// ---------------------------------------------------------------------------
// prep_attn: attn[b,:] = softmax_d(x_score[b,:]); s_hc and b_attn cancel.
__global__ void prep_attn_kernel(const float* __restrict__ x, const float* __restrict__ Wattn,
                                 float* __restrict__ attn) {
    __shared__ float wx[T_];
    __shared__ float red[256];
    int b = blockIdx.x, d = threadIdx.x;
    if (d < T_) wx[d] = Wattn[2 * H_ + d];
    __syncthreads();
    const float* xb = x + (size_t)b * T_ * D_ + d;
    float s = 0.f;
    #pragma unroll
    for (int t = 0; t < T_; ++t) s += xb[t * D_] * wx[t];
    red[d] = s;
    __syncthreads();
    for (int o = 128; o > 0; o >>= 1) {
        if (d < o) red[d] = fmaxf(red[d], red[d + o]);
        __syncthreads();
    }
    float m = red[0];
    __syncthreads();
    float e = __expf(s - m);
    red[d] = e;
    __syncthreads();
    for (int o = 128; o > 0; o >>= 1) {
        if (d < o) red[d] += red[d + o];
        __syncthreads();
    }
    attn[b * D_ + d] = e * (1.f / red[0]);
}

// ---------------------------------------------------------------------------
// winw: w_in = attn (*) x. f32 out ([b][t][d]) + bf16 copy [t][b][d] for GEMM.
__global__ void winw_kernel(const float* __restrict__ x, const float* __restrict__ attn,
                            float* __restrict__ w_out, unsigned short* __restrict__ win_bf) {
    int i4 = blockIdx.x * 256 + threadIdx.x;  // [0, B*T*D/4)
    int e  = i4 * 4;
    int d  = e & 255;
    int bt = e >> 8;            // b*64 + t
    int b  = bt >> 6, t = bt & 63;
    f32x4 xv = *(const f32x4*)(x + e);
    f32x4 av = *(const f32x4*)(attn + b * D_ + d);
    f32x4 w  = xv * av;
    *(f32x4*)(w_out + e) = w;
    ushort4 u;
    u.x = f2bf(w[0]); u.y = f2bf(w[1]); u.z = f2bf(w[2]); u.w = f2bf(w[3]);
    *(ushort4*)(win_bf + ((size_t)(t * B_ + b) * D_ + d)) = u;
}

// ---------------------------------------------------------------------------
// gemmx: pre_gates[m][n] = sum_k w_in[m][k] * W_ih[n][k] + bias[n], m = t*1024+b.
__global__ __launch_bounds__(256, 2) void gemmx_kernel(const unsigned short* __restrict__ A,
                                                       const unsigned short* __restrict__ Bw,
                                                       const float* __restrict__ bias,
                                                       unsigned short* __restrict__ pre) {
    int bx = blockIdx.x;               // 4096 = 512 x 8
    int bn = bx & 7, bm = bx >> 3;
    int tid = threadIdx.x, lane = tid & 63, w = tid >> 6;
    int wr = w >> 1, wc = w & 1;
    int m0 = bm * 128 + wr * 64, n0 = bn * 128 + wc * 64;
    int lr = lane & 15, lk = (lane >> 4) * 8;

    const unsigned short* Ab[4];
    const unsigned short* Bb[4];
    float biasv[4];
    #pragma unroll
    for (int i = 0; i < 4; ++i) {
        Ab[i] = A  + (size_t)(m0 + i * 16 + lr) * D_ + lk;
        Bb[i] = Bw + (size_t)(n0 + i * 16 + lr) * D_ + lk;
        biasv[i] = bias[n0 + i * 16 + lr];
    }
    f32x4 acc[4][4] = {};
    #pragma unroll
    for (int kk = 0; kk < 8; ++kk) {
        bf16x8 a[4], bb[4];
        #pragma unroll
        for (int i = 0; i < 4; ++i) {
            a[i]  = *(const bf16x8*)(Ab[i] + kk * 32);
            bb[i] = *(const bf16x8*)(Bb[i] + kk * 32);
        }
        #pragma unroll
        for (int mi = 0; mi < 4; ++mi)
            #pragma unroll
            for (int ni = 0; ni < 4; ++ni)
                acc[mi][ni] = __builtin_amdgcn_mfma_f32_16x16x32_bf16(a[mi], bb[ni], acc[mi][ni], 0, 0, 0);
    }
    int orow = (lane >> 4) * 4;
    #pragma unroll
    for (int mi = 0; mi < 4; ++mi)
        #pragma unroll
        for (int ni = 0; ni < 4; ++ni)
            #pragma unroll
            for (int q = 0; q < 4; ++q) {
                int m = m0 + mi * 16 + orow + q;
                int n = n0 + ni * 16 + lr;
                pre[(size_t)m * G_ + n] = f2bf(acc[mi][ni][q] + biasv[ni]);
            }
}

// ---------------------------------------------------------------------------
// seqs v11: occupancy over residency. 64 blocks x 1024 threads (16 waves,
// 4 waves/SIMD). Wave w owns h-cols [w*16, w*16+16): 4 n-tiles (one per
// gate). Tile g=0 lives in LDS frag layout (16 x 8KB = 128 KB); g=1..3 are
// streamed from XCD-L2 via a rolling half-K buffer (48 VGPRs). Arch demand
// ~115 < 128 cap at 4 waves/SIMD -> no spill (watch VGPR_Count < 128).
// Cell work halves per thread (4 q). h parity-dbuf in LDS frag layout, one
// lgkm-only barrier per step; pre-gates pair-loaded at step top (K-loop of
// cover); next-step kk0-3 stream loads cross the barrier in flight.
__global__ __launch_bounds__(1024)
__attribute__((amdgpu_waves_per_eu(4, 4)))
void seqs_kernel(const unsigned short* __restrict__ pre,
                 const unsigned short* __restrict__ Whh,
                 float* __restrict__ enc_out) {
    extern __shared__ char smem[];
    unsigned short* W_frag = (unsigned short*)smem;              // [16 tile][8kk][64lane][8] = 131072 B
    unsigned short* h_frag = (unsigned short*)(smem + 131072);   // [2par][8kk][64lane][8] = 16384 B

    int tid = threadIdx.x, lane = tid & 63, w = tid >> 6;   // w in [0,16)
    int lr = lane & 15, hi = lane >> 4;
    int r0 = blockIdx.x * 16;

    // stage g=0 tile (B-row n = w*16 + lr) into LDS fragment layout
    {
        const unsigned short* src = Whh + (size_t)(w * 16 + lr) * 256 + hi * 8;
        #pragma unroll
        for (int c = 0; c < 8; ++c)
            *(u32x4*)&W_frag[((w * 8 + c) * 64 + lane) * 8] = *(const u32x4*)(src + c * 32);
    }
    // zero h (both parities): 4096 dwords
    for (int i = tid; i < 4096; i += 1024) ((unsigned int*)h_frag)[i] = 0;

    // stream bases for g=1,2,3 (B-row n = g*256 + w*16 + lr)
    const unsigned short* Wg1 = Whh + (size_t)(1 * 256 + w * 16 + lr) * 256 + hi * 8;
    const unsigned short* Wg2 = Whh + (size_t)(2 * 256 + w * 16 + lr) * 256 + hi * 8;
    const unsigned short* Wg3 = Whh + (size_t)(3 * 256 + w * 16 + lr) * 256 + hi * 8;
    bf16x8 sb1[4], sb2[4], sb3[4];   // rolling half-K buffer (48 regs)
    #pragma unroll
    for (int k2 = 0; k2 < 4; ++k2) {
        sb1[k2] = *(const bf16x8*)(Wg1 + k2 * 32);
        sb2[k2] = *(const bf16x8*)(Wg2 + k2 * 32);
        sb3[k2] = *(const bf16x8*)(Wg3 + k2 * 32);
    }

    // pre-gate pair-load base: lane covers col pair (lr&14, lr&14|1)
    const unsigned short* ppair = pre + (size_t)(r0 + hi * 4) * G_ + w * 16 + (lr & 14);
    unsigned int sel = lr & 1;
    float cst[4] = {};

    __syncthreads();

    #pragma unroll 1
    for (int t = 0; t < T_; ++t) {
        // pre-gates for this step (cover = the whole K-loop)
        const unsigned short* Ps = ppair + (size_t)t * (1024u * 1024u);
        unsigned int pg[16];
        #pragma unroll
        for (int g = 0; g < 4; ++g)
            #pragma unroll
            for (int q = 0; q < 4; ++q)
                pg[g * 4 + q] = *(const unsigned int*)(Ps + (size_t)q * 1024 + g * 256);

        int p = t & 1;
        const unsigned short* hrd = h_frag + p * 4096;
        unsigned short*       hwr = h_frag + (p ^ 1) * 4096;

        f32x4 acc[4] = {};
        // phase 1: kk0-3 (sbuf holds kk0-3, loaded last step — full cover)
        #pragma unroll
        for (int kk = 0; kk < 4; ++kk) {
            bf16x8 a  = *(const bf16x8*)&hrd[(kk * 64 + lane) * 8];
            bf16x8 b0 = *(const bf16x8*)&W_frag[((w * 8 + kk) * 64 + lane) * 8];
            acc[0] = __builtin_amdgcn_mfma_f32_16x16x32_bf16(a, b0, acc[0], 0, 0, 0);
            acc[1] = __builtin_amdgcn_mfma_f32_16x16x32_bf16(a, sb1[kk], acc[1], 0, 0, 0);
            acc[2] = __builtin_amdgcn_mfma_f32_16x16x32_bf16(a, sb2[kk], acc[2], 0, 0, 0);
            acc[3] = __builtin_amdgcn_mfma_f32_16x16x32_bf16(a, sb3[kk], acc[3], 0, 0, 0);
        }
        // reload kk4-7 (stall here is covered by the 3 sibling waves/SIMD)
        #pragma unroll
        for (int k2 = 0; k2 < 4; ++k2) {
            sb1[k2] = *(const bf16x8*)(Wg1 + (k2 + 4) * 32);
            sb2[k2] = *(const bf16x8*)(Wg2 + (k2 + 4) * 32);
            sb3[k2] = *(const bf16x8*)(Wg3 + (k2 + 4) * 32);
        }
        // phase 2: kk4-7
        #pragma unroll
        for (int kk = 4; kk < 8; ++kk) {
            bf16x8 a  = *(const bf16x8*)&hrd[(kk * 64 + lane) * 8];
            bf16x8 b0 = *(const bf16x8*)&W_frag[((w * 8 + kk) * 64 + lane) * 8];
            acc[0] = __builtin_amdgcn_mfma_f32_16x16x32_bf16(a, b0, acc[0], 0, 0, 0);
            acc[1] = __builtin_amdgcn_mfma_f32_16x16x32_bf16(a, sb1[kk - 4], acc[1], 0, 0, 0);
            acc[2] = __builtin_amdgcn_mfma_f32_16x16x32_bf16(a, sb2[kk - 4], acc[2], 0, 0, 0);
            acc[3] = __builtin_amdgcn_mfma_f32_16x16x32_bf16(a, sb3[kk - 4], acc[3], 0, 0, 0);
        }
        // reload kk0-3 for NEXT step (stays in flight across the barrier)
        #pragma unroll
        for (int k2 = 0; k2 < 4; ++k2) {
            sb1[k2] = *(const bf16x8*)(Wg1 + k2 * 32);
            sb2[k2] = *(const bf16x8*)(Wg2 + k2 * 32);
            sb3[k2] = *(const bf16x8*)(Wg3 + k2 * 32);
        }

        // cell update: rows hi*4+q, col w*16+lr (4 q per thread)
        #pragma unroll
        for (int q = 0; q < 4; ++q) {
            float gi = acc[0][q] + __builtin_bit_cast(float, sel ? (pg[0 * 4 + q] & 0xffff0000u) : (pg[0 * 4 + q] << 16));
            float gf = acc[1][q] + __builtin_bit_cast(float, sel ? (pg[1 * 4 + q] & 0xffff0000u) : (pg[1 * 4 + q] << 16));
            float gg = acc[2][q] + __builtin_bit_cast(float, sel ? (pg[2 * 4 + q] & 0xffff0000u) : (pg[2 * 4 + q] << 16));
            float go = acc[3][q] + __builtin_bit_cast(float, sel ? (pg[3 * 4 + q] & 0xffff0000u) : (pg[3 * 4 + q] << 16));
            float si = RCP(1.f + __expf(-gi));
            float sf = RCP(1.f + __expf(-gf));
            float so = RCP(1.f + __expf(-go));
            float tg = 1.f - 2.f * RCP(__expf(2.f * gg) + 1.f);
            float cn = sf * cst[q] + si * tg;
            cst[q] = cn;
            float tc = 1.f - 2.f * RCP(__expf(2.f * cn) + 1.f);
            float h  = so * tc;
            unsigned int hu = (unsigned int)f2bf(h);
            unsigned int ph = (unsigned int)__shfl_xor((int)hu, 1);
            if ((lr & 1) == 0) {
                // h[row=hi*4+q][col=w*16+lr] in frag layout:
                // kk = w>>1, lane' = ((w&1)*2 + (lr>>3))*16 + row, e = lr&7
                unsigned int dw = hu | (ph << 16);
                *(unsigned int*)&hwr[(w >> 1) * 512 +
                                     (((w & 1) * 2 + (lr >> 3)) * 16 + hi * 4 + q) * 8 + (lr & 7)] = dw;
            }
            enc_out[((size_t)(r0 + hi * 4 + q) * T_ + t) * H_ + w * 16 + lr] = h;
        }

        // end of step: only LDS must drain; vmem (stream + stores) stays live
        asm volatile("s_waitcnt lgkmcnt(0)" ::: "memory");
        __builtin_amdgcn_s_barrier();
        __builtin_amdgcn_sched_barrier(0);
    }
}

// ---------------------------------------------------------------------------
extern "C" void kernel_launch(void* const* d_in, const int* in_sizes, int n_in,
                              void* d_out, int out_size, void* d_ws, size_t ws_size,
                              hipStream_t stream) {
    const float* x     = (const float*)d_in[0];
    const float* Wattn = (const float*)d_in[1];
    // d_in[2] = b_attn (cancels in softmax)
    const float* Wih   = (const float*)d_in[3];
    const float* Whh   = (const float*)d_in[4];
    const float* bih   = (const float*)d_in[5];
    const float* bhh   = (const float*)d_in[6];

    char* ws = (char*)d_ws;
    float*          attn   = (float*)(ws);                            // 1 MB
    unsigned short* win_bf = (unsigned short*)(ws + 1048576);         // 32 MB [t][b][d]
    unsigned short* wih_bf = (unsigned short*)(ws + 34603008);        // 512 KB
    unsigned short* whh_bf = (unsigned short*)(ws + 35127296);        // 512 KB
    float*          bias   = (float*)(ws + 35651584);                 // 4 KB
    unsigned short* pre    = (unsigned short*)(ws + 35659776);        // 128 MB [t][b][n]

    float* w_out   = (float*)d_out;                                   // output 0
    float* enc_out = (float*)d_out + (size_t)B_ * T_ * D_;            // output 1

    hipFuncSetAttribute((const void*)seqs_kernel,
                        hipFuncAttributeMaxDynamicSharedMemorySize, 147456);

    prep_w_kernel<<<dim3(1024), dim3(256), 0, stream>>>(Wih, Whh, bih, bhh, wih_bf, whh_bf, bias);
    prep_attn_kernel<<<dim3(1024), dim3(256), 0, stream>>>(x, Wattn, attn);
    winw_kernel<<<dim3(16384), dim3(256), 0, stream>>>(x, attn, w_out, win_bf);
    gemmx_kernel<<<dim3(4096), dim3(256), 0, stream>>>(win_bf, wih_bf, bias, pre);
    seqs_kernel<<<dim3(64), dim3(1024), 147456, stream>>>(pre, whh_bf, enc_out);
}